// Round 1
// baseline (364.065 us; speedup 1.0000x reference)
//
#include <hip/hip_runtime.h>
#include <hip/hip_bf16.h>
#include <cstddef>

#define GAT_B 16
#define GAT_N 2048
#define GAT_D 128
#define GAT_ROWS (GAT_B * GAT_N)
#define CH 32           // chunks per batch for cumsum
#define CL (GAT_N / CH) // 64 positions per chunk
#define GAT_ALPHA 0.2f

// ---------------------------------------------------------------------------
// K1: h = x @ W (fp32), s1 = h . a1, s2 = h . a2
// block = 256 threads (4 waves); each wave computes 4 rows; 16 rows/block.
// W staged in LDS [k][d] (b32 reads, lane -> d: 2 lanes/bank = free).
// ---------------------------------------------------------------------------
__global__ __launch_bounds__(256) void k1_gemm(const float* __restrict__ x,
                                               const float* __restrict__ W,
                                               const float* __restrict__ aa,
                                               float* __restrict__ h,
                                               float* __restrict__ s1,
                                               float* __restrict__ s2) {
  __shared__ float Wl[128 * 128];
  __shared__ float xs[4][4][128];
  const int tid = threadIdx.x;
  for (int i = tid; i < 128 * 128; i += 256) Wl[i] = W[i];
  const int wave = tid >> 6, lane = tid & 63;
  const int row0 = blockIdx.x * 16 + wave * 4;
#pragma unroll
  for (int rr = 0; rr < 4; ++rr) {
    ((float2*)&xs[wave][rr][0])[lane] =
        ((const float2*)(x + (size_t)(row0 + rr) * GAT_D))[lane];
  }
  __syncthreads();
  float acc0[4] = {0.f, 0.f, 0.f, 0.f};
  float acc1[4] = {0.f, 0.f, 0.f, 0.f};
  for (int k = 0; k < 128; k += 4) {
    float4 xv[4];
#pragma unroll
    for (int rr = 0; rr < 4; ++rr) xv[rr] = *(const float4*)&xs[wave][rr][k];
#pragma unroll
    for (int kk = 0; kk < 4; ++kk) {
      const float w0 = Wl[(k + kk) * 128 + lane];
      const float w1 = Wl[(k + kk) * 128 + lane + 64];
#pragma unroll
      for (int rr = 0; rr < 4; ++rr) {
        const float xr = ((const float*)&xv[rr])[kk];
        acc0[rr] = fmaf(xr, w0, acc0[rr]);
        acc1[rr] = fmaf(xr, w1, acc1[rr]);
      }
    }
  }
  const float a1l = aa[lane], a1h = aa[lane + 64];
  const float a2l = aa[128 + lane], a2h = aa[192 + lane];
#pragma unroll
  for (int rr = 0; rr < 4; ++rr) {
    const size_t base = (size_t)(row0 + rr) * GAT_D;
    h[base + lane] = acc0[rr];
    h[base + lane + 64] = acc1[rr];
    float p1 = acc0[rr] * a1l + acc1[rr] * a1h;
    float p2 = acc0[rr] * a2l + acc1[rr] * a2h;
#pragma unroll
    for (int off = 32; off > 0; off >>= 1) {
      p1 += __shfl_down(p1, off);
      p2 += __shfl_down(p2, off);
    }
    if (lane == 0) {
      s1[row0 + rr] = p1;
      s2[row0 + rr] = p2;
    }
  }
}

// ---------------------------------------------------------------------------
// K2: per batch -- bitonic sort of s2 (2048) with indices, then scalar
// denominator scans: preDenA[p] = sum_{q<=p} exp(alpha*s2s[q]),
//                    sufDenP[p] = sum_{q>=p} exp(s2s[q]).
// one block (1024 threads) per batch.
// ---------------------------------------------------------------------------
__global__ __launch_bounds__(1024) void k2_sort(const float* __restrict__ s2,
                                                float* __restrict__ s2s,
                                                int* __restrict__ idxs,
                                                float* __restrict__ preDenA,
                                                float* __restrict__ sufDenP) {
  __shared__ float v[2048];
  __shared__ int id[2048];
  __shared__ float sa[2048];
  __shared__ float sb[2048];
  const int tid = threadIdx.x;
  const int b = blockIdx.x;
  const int i0 = tid, i1 = tid + 1024;
  v[i0] = s2[b * GAT_N + i0];
  v[i1] = s2[b * GAT_N + i1];
  id[i0] = i0;
  id[i1] = i1;
  for (int k = 2; k <= 2048; k <<= 1) {
    for (int j = k >> 1; j > 0; j >>= 1) {
      __syncthreads();
      const int i = ((tid & ~(j - 1)) << 1) | (tid & (j - 1));
      const int ixj = i | j;
      const bool up = (i & k) == 0;
      const float va = v[i], vb = v[ixj];
      if (up ? (va > vb) : (va < vb)) {
        v[i] = vb;
        v[ixj] = va;
        const int ta = id[i];
        id[i] = id[ixj];
        id[ixj] = ta;
      }
    }
  }
  __syncthreads();
  s2s[b * GAT_N + i0] = v[i0];
  s2s[b * GAT_N + i1] = v[i1];
  idxs[b * GAT_N + i0] = id[i0];
  idxs[b * GAT_N + i1] = id[i1];

  // inclusive prefix scan of exp(alpha * v)
  sa[i0] = __expf(GAT_ALPHA * v[i0]);
  sa[i1] = __expf(GAT_ALPHA * v[i1]);
  float* src = sa;
  float* dst = sb;
  for (int off = 1; off < 2048; off <<= 1) {
    __syncthreads();
    const float r0 = src[i0] + (i0 >= off ? src[i0 - off] : 0.f);
    const float r1 = src[i1] + (i1 >= off ? src[i1 - off] : 0.f);
    dst[i0] = r0;
    dst[i1] = r1;
    float* t = src;
    src = dst;
    dst = t;
  }
  preDenA[b * GAT_N + i0] = src[i0];  // own writes, no sync needed
  preDenA[b * GAT_N + i1] = src[i1];

  // inclusive suffix scan of exp(v); dst is the free buffer
  dst[i0] = __expf(v[i0]);
  dst[i1] = __expf(v[i1]);
  {
    float* t = src;
    src = dst;
    dst = t;
  }
  for (int off = 1; off < 2048; off <<= 1) {
    __syncthreads();
    const float r0 = src[i0] + (i0 + off < 2048 ? src[i0 + off] : 0.f);
    const float r1 = src[i1] + (i1 + off < 2048 ? src[i1 + off] : 0.f);
    dst[i0] = r0;
    dst[i1] = r1;
    float* t = src;
    src = dst;
    dst = t;
  }
  sufDenP[b * GAT_N + i0] = src[i0];
  sufDenP[b * GAT_N + i1] = src[i1];
}

// ---------------------------------------------------------------------------
// K3: per-(batch,chunk) partial sums of w*h over the chunk (both weightings).
// ---------------------------------------------------------------------------
__global__ __launch_bounds__(128) void k3_partial(const float* __restrict__ h,
                                                  const float* __restrict__ s2s,
                                                  const int* __restrict__ idxs,
                                                  float* __restrict__ partP,
                                                  float* __restrict__ partA) {
  const int b = blockIdx.x >> 5, c = blockIdx.x & 31;
  const int d = threadIdx.x;
  const int q0 = c * CL;
  const float* s2sb = s2s + b * GAT_N;
  const int* idxb = idxs + b * GAT_N;
  const float* hb = h + (size_t)b * GAT_N * GAT_D;
  float accP = 0.f, accA = 0.f;
#pragma unroll 4
  for (int q = q0; q < q0 + CL; ++q) {
    const float sv = s2sb[q];
    const int j = idxb[q];
    const float hv = hb[(size_t)j * GAT_D + d];
    accP = fmaf(__expf(sv), hv, accP);
    accA = fmaf(__expf(GAT_ALPHA * sv), hv, accA);
  }
  partP[(b * CH + c) * GAT_D + d] = accP;
  partA[(b * CH + c) * GAT_D + d] = accA;
}

// ---------------------------------------------------------------------------
// K4: emit full vector cumsums.
//   PreA[p][d] = sum_{q<=p} exp(alpha*s2s[q]) * h[idx[q]][d]   (prefix)
//   SufP[p][d] = sum_{q>=p} exp(s2s[q])       * h[idx[q]][d]   (suffix)
// ---------------------------------------------------------------------------
__global__ __launch_bounds__(128) void k4_emit(const float* __restrict__ h,
                                               const float* __restrict__ s2s,
                                               const int* __restrict__ idxs,
                                               const float* __restrict__ partP,
                                               const float* __restrict__ partA,
                                               float* __restrict__ PreA,
                                               float* __restrict__ SufP) {
  const int b = blockIdx.x >> 5, c = blockIdx.x & 31;
  const int d = threadIdx.x;
  const int q0 = c * CL;
  float offA = 0.f, offP = 0.f;
  for (int cc = 0; cc < c; ++cc) offA += partA[(b * CH + cc) * GAT_D + d];
  for (int cc = c + 1; cc < CH; ++cc) offP += partP[(b * CH + cc) * GAT_D + d];
  const float* s2sb = s2s + b * GAT_N;
  const int* idxb = idxs + b * GAT_N;
  const float* hb = h + (size_t)b * GAT_N * GAT_D;
  float acc = offA;
#pragma unroll 4
  for (int q = q0; q < q0 + CL; ++q) {
    acc = fmaf(__expf(GAT_ALPHA * s2sb[q]), hb[(size_t)idxb[q] * GAT_D + d], acc);
    PreA[((size_t)b * GAT_N + q) * GAT_D + d] = acc;
  }
  acc = offP;
#pragma unroll 4
  for (int q = q0 + CL - 1; q >= q0; --q) {
    acc = fmaf(__expf(s2sb[q]), hb[(size_t)idxb[q] * GAT_D + d], acc);
    SufP[((size_t)b * GAT_N + q) * GAT_D + d] = acc;
  }
}

// ---------------------------------------------------------------------------
// K5: per row -- binary search split point, combine suffix/prefix sums,
// normalize, relu. one wave per row.
// ---------------------------------------------------------------------------
__global__ __launch_bounds__(256) void k5_out(const float* __restrict__ s1,
                                              const float* __restrict__ s2s,
                                              const float* __restrict__ preDenA,
                                              const float* __restrict__ sufDenP,
                                              const float* __restrict__ PreA,
                                              const float* __restrict__ SufP,
                                              float* __restrict__ out) {
  const int wave = threadIdx.x >> 6, lane = threadIdx.x & 63;
  const int r = blockIdx.x * 4 + wave;
  const int b = r >> 11;
  const float s1v = s1[r];
  const float* s2sb = s2s + b * GAT_N;
  const float t = -s1v;
  int lo = 0, hi = GAT_N;
  while (lo < hi) {
    const int mid = (lo + hi) >> 1;
    if (s2sb[mid] < t)
      lo = mid + 1;
    else
      hi = mid;
  }
  const int p = lo;  // first sorted pos with s2 >= -s1 (plain branch)
  const float e1 = __expf(s1v), e2 = __expf(GAT_ALPHA * s1v);
  float den = 0.f, n0 = 0.f, n1 = 0.f;
  if (p < GAT_N) {
    den = fmaf(e1, sufDenP[b * GAT_N + p], den);
    const float* sp = SufP + ((size_t)b * GAT_N + p) * GAT_D;
    n0 = fmaf(e1, sp[lane], n0);
    n1 = fmaf(e1, sp[lane + 64], n1);
  }
  if (p > 0) {
    den = fmaf(e2, preDenA[b * GAT_N + p - 1], den);
    const float* pa = PreA + ((size_t)b * GAT_N + p - 1) * GAT_D;
    n0 = fmaf(e2, pa[lane], n0);
    n1 = fmaf(e2, pa[lane + 64], n1);
  }
  const float inv = 1.f / den;
  out[(size_t)r * GAT_D + lane] = fmaxf(n0 * inv, 0.f);
  out[(size_t)r * GAT_D + lane + 64] = fmaxf(n1 * inv, 0.f);
}

extern "C" void kernel_launch(void* const* d_in, const int* in_sizes, int n_in,
                              void* d_out, int out_size, void* d_ws, size_t ws_size,
                              hipStream_t stream) {
  (void)in_sizes;
  (void)n_in;
  (void)out_size;
  const float* x = (const float*)d_in[0];
  const float* W = (const float*)d_in[1];
  const float* a = (const float*)d_in[2];
  float* out = (float*)d_out;
  float* wsf = (float*)d_ws;

  const size_t HN = (size_t)GAT_ROWS * GAT_D;
  size_t o = 0;
  float* s1v = wsf + o;     o += GAT_ROWS;
  float* s2v = wsf + o;     o += GAT_ROWS;
  float* s2s = wsf + o;     o += GAT_ROWS;
  int* idxs = (int*)(wsf + o); o += GAT_ROWS;
  float* preDenA = wsf + o; o += GAT_ROWS;
  float* sufDenP = wsf + o; o += GAT_ROWS;
  float* PreA = wsf + o;    o += HN;
  float* SufP = wsf + o;    o += HN;
  float* partP = wsf + o;   o += GAT_B * CH * GAT_D;
  float* partA = wsf + o;   o += GAT_B * CH * GAT_D;
  float* h;
  if (ws_size >= (o + HN) * sizeof(float)) {
    h = wsf + o;
  } else {
    h = out;  // K5 never reads h; safe to reuse the output buffer as scratch
  }

  k1_gemm<<<GAT_ROWS / 16, 256, 0, stream>>>(x, W, a, h, s1v, s2v);
  k2_sort<<<GAT_B, 1024, 0, stream>>>(s2v, s2s, idxs, preDenA, sufDenP);
  k3_partial<<<GAT_B * CH, 128, 0, stream>>>(h, s2s, idxs, partP, partA);
  k4_emit<<<GAT_B * CH, 128, 0, stream>>>(h, s2s, idxs, partP, partA, PreA, SufP);
  k5_out<<<GAT_ROWS / 4, 256, 0, stream>>>(s1v, s2s, preDenA, sufDenP, PreA, SufP, out);
}

// Round 2
// 115.161 us; speedup vs baseline: 3.1614x; 3.1614x over previous
//
#include <hip/hip_runtime.h>
#include <hip/hip_bf16.h>
#include <cstddef>

#define GAT_B 16
#define GAT_N 2048
#define GAT_D 128
#define GAT_ROWS (GAT_B * GAT_N)
#define CH 32           // chunks per batch for cumsum
#define CL (GAT_N / CH) // 64 positions per chunk
#define GAT_ALPHA 0.2f

// ---------------------------------------------------------------------------
// K1: h = x @ W (fp32), s1 = h . a1, s2 = h . a2
// 512 blocks x 256 threads (4 waves). Each block: stage W (64KB) in LDS once,
// then 4 passes of 16 rows (4 rows/wave). Per thread: 4 rows x 2 cols.
// LDS: 64KB W + 8KB x = 72KB -> 2 blocks/CU resident (grid fully resident).
// k-loop: #pragma unroll 2 -- the previous version's full unroll spilled
// (VGPR=256 + 640MB scratch traffic).
// ---------------------------------------------------------------------------
__global__ __launch_bounds__(256, 2) void k1_gemm(const float* __restrict__ x,
                                                  const float* __restrict__ W,
                                                  const float* __restrict__ aa,
                                                  float* __restrict__ h,
                                                  float* __restrict__ s1,
                                                  float* __restrict__ s2) {
  __shared__ float Wl[128][128];  // [k][d]
  __shared__ float xs[16][128];
  const int tid = threadIdx.x;
  // stage W: coalesced float4 reads + float4 LDS writes (16 iters/thread)
  for (int i = tid * 4; i < 128 * 128; i += 1024) {
    *(float4*)&Wl[i >> 7][i & 127] = *(const float4*)(W + i);
  }
  const int wave = tid >> 6, lane = tid & 63;
  const float a1l = aa[lane], a1h = aa[lane + 64];
  const float a2l = aa[128 + lane], a2h = aa[192 + lane];

  for (int pass = 0; pass < 4; ++pass) {
    const int row0 = blockIdx.x * 64 + pass * 16;
    __syncthreads();  // xs reuse + (pass 0) W ready
    for (int i = tid * 4; i < 16 * 128; i += 1024) {
      *(float4*)&xs[i >> 7][i & 127] =
          *(const float4*)(x + (size_t)(row0 + (i >> 7)) * GAT_D + (i & 127));
    }
    __syncthreads();
    const int wr0 = wave * 4;
    float acc0[4] = {0.f, 0.f, 0.f, 0.f};
    float acc1[4] = {0.f, 0.f, 0.f, 0.f};
#pragma unroll 2
    for (int k = 0; k < 128; k += 4) {
      float4 xv[4];
#pragma unroll
      for (int rr = 0; rr < 4; ++rr) xv[rr] = *(const float4*)&xs[wr0 + rr][k];
#pragma unroll
      for (int kk = 0; kk < 4; ++kk) {
        const float w0 = Wl[k + kk][lane];
        const float w1 = Wl[k + kk][lane + 64];
#pragma unroll
        for (int rr = 0; rr < 4; ++rr) {
          const float xr = ((const float*)&xv[rr])[kk];
          acc0[rr] = fmaf(xr, w0, acc0[rr]);
          acc1[rr] = fmaf(xr, w1, acc1[rr]);
        }
      }
    }
#pragma unroll
    for (int rr = 0; rr < 4; ++rr) {
      const int row = row0 + wr0 + rr;
      const size_t base = (size_t)row * GAT_D;
      h[base + lane] = acc0[rr];
      h[base + lane + 64] = acc1[rr];
      float p1 = acc0[rr] * a1l + acc1[rr] * a1h;
      float p2 = acc0[rr] * a2l + acc1[rr] * a2h;
#pragma unroll
      for (int off = 32; off > 0; off >>= 1) {
        p1 += __shfl_down(p1, off);
        p2 += __shfl_down(p2, off);
      }
      if (lane == 0) {
        s1[row] = p1;
        s2[row] = p2;
      }
    }
  }
}

// ---------------------------------------------------------------------------
// K2: per batch -- bitonic sort of s2 (2048) with indices, then scalar
// denominator scans: preDenA[p] = sum_{q<=p} exp(alpha*s2s[q]),
//                    sufDenP[p] = sum_{q>=p} exp(s2s[q]).
// one block (1024 threads) per batch.
// ---------------------------------------------------------------------------
__global__ __launch_bounds__(1024) void k2_sort(const float* __restrict__ s2,
                                                float* __restrict__ s2s,
                                                int* __restrict__ idxs,
                                                float* __restrict__ preDenA,
                                                float* __restrict__ sufDenP) {
  __shared__ float v[2048];
  __shared__ int id[2048];
  __shared__ float sa[2048];
  __shared__ float sb[2048];
  const int tid = threadIdx.x;
  const int b = blockIdx.x;
  const int i0 = tid, i1 = tid + 1024;
  v[i0] = s2[b * GAT_N + i0];
  v[i1] = s2[b * GAT_N + i1];
  id[i0] = i0;
  id[i1] = i1;
  for (int k = 2; k <= 2048; k <<= 1) {
    for (int j = k >> 1; j > 0; j >>= 1) {
      __syncthreads();
      const int i = ((tid & ~(j - 1)) << 1) | (tid & (j - 1));
      const int ixj = i | j;
      const bool up = (i & k) == 0;
      const float va = v[i], vb = v[ixj];
      if (up ? (va > vb) : (va < vb)) {
        v[i] = vb;
        v[ixj] = va;
        const int ta = id[i];
        id[i] = id[ixj];
        id[ixj] = ta;
      }
    }
  }
  __syncthreads();
  s2s[b * GAT_N + i0] = v[i0];
  s2s[b * GAT_N + i1] = v[i1];
  idxs[b * GAT_N + i0] = id[i0];
  idxs[b * GAT_N + i1] = id[i1];

  // inclusive prefix scan of exp(alpha * v)
  sa[i0] = __expf(GAT_ALPHA * v[i0]);
  sa[i1] = __expf(GAT_ALPHA * v[i1]);
  float* src = sa;
  float* dst = sb;
  for (int off = 1; off < 2048; off <<= 1) {
    __syncthreads();
    const float r0 = src[i0] + (i0 >= off ? src[i0 - off] : 0.f);
    const float r1 = src[i1] + (i1 >= off ? src[i1 - off] : 0.f);
    dst[i0] = r0;
    dst[i1] = r1;
    float* t = src;
    src = dst;
    dst = t;
  }
  preDenA[b * GAT_N + i0] = src[i0];  // own writes, no sync needed
  preDenA[b * GAT_N + i1] = src[i1];

  // inclusive suffix scan of exp(v); dst is the free buffer
  dst[i0] = __expf(v[i0]);
  dst[i1] = __expf(v[i1]);
  {
    float* t = src;
    src = dst;
    dst = t;
  }
  for (int off = 1; off < 2048; off <<= 1) {
    __syncthreads();
    const float r0 = src[i0] + (i0 + off < 2048 ? src[i0 + off] : 0.f);
    const float r1 = src[i1] + (i1 + off < 2048 ? src[i1 + off] : 0.f);
    dst[i0] = r0;
    dst[i1] = r1;
    float* t = src;
    src = dst;
    dst = t;
  }
  sufDenP[b * GAT_N + i0] = src[i0];
  sufDenP[b * GAT_N + i1] = src[i1];
}

// ---------------------------------------------------------------------------
// K3: per-(batch,chunk) partial sums of w*h over the chunk (both weightings).
// ---------------------------------------------------------------------------
__global__ __launch_bounds__(128) void k3_partial(const float* __restrict__ h,
                                                  const float* __restrict__ s2s,
                                                  const int* __restrict__ idxs,
                                                  float* __restrict__ partP,
                                                  float* __restrict__ partA) {
  const int b = blockIdx.x >> 5, c = blockIdx.x & 31;
  const int d = threadIdx.x;
  const int q0 = c * CL;
  const float* s2sb = s2s + b * GAT_N;
  const int* idxb = idxs + b * GAT_N;
  const float* hb = h + (size_t)b * GAT_N * GAT_D;
  float accP = 0.f, accA = 0.f;
#pragma unroll 4
  for (int q = q0; q < q0 + CL; ++q) {
    const float sv = s2sb[q];
    const int j = idxb[q];
    const float hv = hb[(size_t)j * GAT_D + d];
    accP = fmaf(__expf(sv), hv, accP);
    accA = fmaf(__expf(GAT_ALPHA * sv), hv, accA);
  }
  partP[(b * CH + c) * GAT_D + d] = accP;
  partA[(b * CH + c) * GAT_D + d] = accA;
}

// ---------------------------------------------------------------------------
// K4: emit full vector cumsums.
//   PreA[p][d] = sum_{q<=p} exp(alpha*s2s[q]) * h[idx[q]][d]   (prefix)
//   SufP[p][d] = sum_{q>=p} exp(s2s[q])       * h[idx[q]][d]   (suffix)
// ---------------------------------------------------------------------------
__global__ __launch_bounds__(128) void k4_emit(const float* __restrict__ h,
                                               const float* __restrict__ s2s,
                                               const int* __restrict__ idxs,
                                               const float* __restrict__ partP,
                                               const float* __restrict__ partA,
                                               float* __restrict__ PreA,
                                               float* __restrict__ SufP) {
  const int b = blockIdx.x >> 5, c = blockIdx.x & 31;
  const int d = threadIdx.x;
  const int q0 = c * CL;
  float offA = 0.f, offP = 0.f;
  for (int cc = 0; cc < c; ++cc) offA += partA[(b * CH + cc) * GAT_D + d];
  for (int cc = c + 1; cc < CH; ++cc) offP += partP[(b * CH + cc) * GAT_D + d];
  const float* s2sb = s2s + b * GAT_N;
  const int* idxb = idxs + b * GAT_N;
  const float* hb = h + (size_t)b * GAT_N * GAT_D;
  float acc = offA;
#pragma unroll 4
  for (int q = q0; q < q0 + CL; ++q) {
    acc = fmaf(__expf(GAT_ALPHA * s2sb[q]), hb[(size_t)idxb[q] * GAT_D + d], acc);
    PreA[((size_t)b * GAT_N + q) * GAT_D + d] = acc;
  }
  acc = offP;
#pragma unroll 4
  for (int q = q0 + CL - 1; q >= q0; --q) {
    acc = fmaf(__expf(s2sb[q]), hb[(size_t)idxb[q] * GAT_D + d], acc);
    SufP[((size_t)b * GAT_N + q) * GAT_D + d] = acc;
  }
}

// ---------------------------------------------------------------------------
// K5: per row -- binary search split point, combine suffix/prefix sums,
// normalize, relu. one wave per row.
// ---------------------------------------------------------------------------
__global__ __launch_bounds__(256) void k5_out(const float* __restrict__ s1,
                                              const float* __restrict__ s2s,
                                              const float* __restrict__ preDenA,
                                              const float* __restrict__ sufDenP,
                                              const float* __restrict__ PreA,
                                              const float* __restrict__ SufP,
                                              float* __restrict__ out) {
  const int wave = threadIdx.x >> 6, lane = threadIdx.x & 63;
  const int r = blockIdx.x * 4 + wave;
  const int b = r >> 11;
  const float s1v = s1[r];
  const float* s2sb = s2s + b * GAT_N;
  const float t = -s1v;
  int lo = 0, hi = GAT_N;
  while (lo < hi) {
    const int mid = (lo + hi) >> 1;
    if (s2sb[mid] < t)
      lo = mid + 1;
    else
      hi = mid;
  }
  const int p = lo;  // first sorted pos with s2 >= -s1 (plain branch)
  const float e1 = __expf(s1v), e2 = __expf(GAT_ALPHA * s1v);
  float den = 0.f, n0 = 0.f, n1 = 0.f;
  if (p < GAT_N) {
    den = fmaf(e1, sufDenP[b * GAT_N + p], den);
    const float* sp = SufP + ((size_t)b * GAT_N + p) * GAT_D;
    n0 = fmaf(e1, sp[lane], n0);
    n1 = fmaf(e1, sp[lane + 64], n1);
  }
  if (p > 0) {
    den = fmaf(e2, preDenA[b * GAT_N + p - 1], den);
    const float* pa = PreA + ((size_t)b * GAT_N + p - 1) * GAT_D;
    n0 = fmaf(e2, pa[lane], n0);
    n1 = fmaf(e2, pa[lane + 64], n1);
  }
  const float inv = 1.f / den;
  out[(size_t)r * GAT_D + lane] = fmaxf(n0 * inv, 0.f);
  out[(size_t)r * GAT_D + lane + 64] = fmaxf(n1 * inv, 0.f);
}

extern "C" void kernel_launch(void* const* d_in, const int* in_sizes, int n_in,
                              void* d_out, int out_size, void* d_ws, size_t ws_size,
                              hipStream_t stream) {
  (void)in_sizes;
  (void)n_in;
  (void)out_size;
  const float* x = (const float*)d_in[0];
  const float* W = (const float*)d_in[1];
  const float* a = (const float*)d_in[2];
  float* out = (float*)d_out;
  float* wsf = (float*)d_ws;

  const size_t HN = (size_t)GAT_ROWS * GAT_D;
  size_t o = 0;
  float* s1v = wsf + o;     o += GAT_ROWS;
  float* s2v = wsf + o;     o += GAT_ROWS;
  float* s2s = wsf + o;     o += GAT_ROWS;
  int* idxs = (int*)(wsf + o); o += GAT_ROWS;
  float* preDenA = wsf + o; o += GAT_ROWS;
  float* sufDenP = wsf + o; o += GAT_ROWS;
  float* PreA = wsf + o;    o += HN;
  float* SufP = wsf + o;    o += HN;
  float* partP = wsf + o;   o += GAT_B * CH * GAT_D;
  float* partA = wsf + o;   o += GAT_B * CH * GAT_D;
  float* h;
  if (ws_size >= (o + HN) * sizeof(float)) {
    h = wsf + o;
  } else {
    h = out;  // K5 never reads h; safe to reuse the output buffer as scratch
  }

  k1_gemm<<<512, 256, 0, stream>>>(x, W, a, h, s1v, s2v);
  k2_sort<<<GAT_B, 1024, 0, stream>>>(s2v, s2s, idxs, preDenA, sufDenP);
  k3_partial<<<GAT_B * CH, 128, 0, stream>>>(h, s2s, idxs, partP, partA);
  k4_emit<<<GAT_B * CH, 128, 0, stream>>>(h, s2s, idxs, partP, partA, PreA, SufP);
  k5_out<<<GAT_ROWS / 4, 256, 0, stream>>>(s1v, s2s, preDenA, sufDenP, PreA, SufP, out);
}

// Round 3
// 104.505 us; speedup vs baseline: 3.4837x; 1.1020x over previous
//
#include <hip/hip_runtime.h>
#include <hip/hip_bf16.h>
#include <cstddef>

#define GAT_B 16
#define GAT_N 2048
#define GAT_D 128
#define GAT_ROWS (GAT_B * GAT_N)
#define CH 64           // chunks per batch for cumsum
#define CL (GAT_N / CH) // 32 positions per chunk
#define GAT_ALPHA 0.2f

// ---------------------------------------------------------------------------
// K1: h = x @ W (fp32), s1 = h . a1, s2 = h . a2
// 1024 blocks x 256 threads. Block tile: 32 rows x 128 cols.
// Thread: 4 rows x 4 cols; W read as ds_read_b128 (4 cols/insn) -> per 4-k
// group 8 b128 (~96 LDS cyc) vs 128 VALU cyc of FMA => VALU-bound (prev
// version was LDS-b32-bound at 94 LDS / 64 VALU cyc).
// LDS 80KB (W 64K + x 16K) -> 2 blocks/CU, 8 waves/CU.
// ---------------------------------------------------------------------------
__global__ __launch_bounds__(256, 2) void k1_gemm(const float* __restrict__ x,
                                                  const float* __restrict__ W,
                                                  const float* __restrict__ aa,
                                                  float* __restrict__ h,
                                                  float* __restrict__ s1,
                                                  float* __restrict__ s2) {
  __shared__ float Wl[128][128];  // [k][d] 64KB
  __shared__ float xs[32][128];   // 16KB
  const int tid = threadIdx.x;
  for (int i = tid * 4; i < 128 * 128; i += 1024)
    *(float4*)&Wl[i >> 7][i & 127] = *(const float4*)(W + i);
  const int row0 = blockIdx.x * 32;
  for (int i = tid * 4; i < 32 * 128; i += 1024)
    *(float4*)&xs[i >> 7][i & 127] = *(const float4*)(x + (size_t)row0 * GAT_D + i);
  __syncthreads();

  const int lane = tid & 63;
  const int c = (tid & 31) << 2;   // 4 cols
  const int rg = (tid >> 5) << 2;  // 4 rows

  float4 acc[4];
#pragma unroll
  for (int r = 0; r < 4; ++r) acc[r] = make_float4(0.f, 0.f, 0.f, 0.f);

#pragma unroll 2
  for (int k = 0; k < 128; k += 4) {
    float4 wv[4], xv[4];
#pragma unroll
    for (int kk = 0; kk < 4; ++kk) wv[kk] = *(const float4*)&Wl[k + kk][c];
#pragma unroll
    for (int r = 0; r < 4; ++r) xv[r] = *(const float4*)&xs[rg + r][k];
#pragma unroll
    for (int r = 0; r < 4; ++r) {
#pragma unroll
      for (int kk = 0; kk < 4; ++kk) {
        const float xr = ((const float*)&xv[r])[kk];
        acc[r].x = fmaf(xr, wv[kk].x, acc[r].x);
        acc[r].y = fmaf(xr, wv[kk].y, acc[r].y);
        acc[r].z = fmaf(xr, wv[kk].z, acc[r].z);
        acc[r].w = fmaf(xr, wv[kk].w, acc[r].w);
      }
    }
  }

  const float4 a1c = *(const float4*)(aa + c);
  const float4 a2c = *(const float4*)(aa + 128 + c);
#pragma unroll
  for (int r = 0; r < 4; ++r) {
    const int row = row0 + rg + r;
    *(float4*)(h + (size_t)row * GAT_D + c) = acc[r];
    float p1 = acc[r].x * a1c.x + acc[r].y * a1c.y + acc[r].z * a1c.z + acc[r].w * a1c.w;
    float p2 = acc[r].x * a2c.x + acc[r].y * a2c.y + acc[r].z * a2c.z + acc[r].w * a2c.w;
#pragma unroll
    for (int off = 1; off < 32; off <<= 1) {
      p1 += __shfl_xor(p1, off);
      p2 += __shfl_xor(p2, off);
    }
    if ((lane & 31) == 0) {
      s1[row] = p1;
      s2[row] = p2;
    }
  }
}

// ---------------------------------------------------------------------------
// K2: per batch -- bitonic sort of s2 (2048) with indices, then BOTH
// denominator scans via one hierarchical shfl scan (2 barriers instead of 22):
//   preDenA[p] = sum_{q<=p} exp(alpha*s2s[q])  (ascending prefix)
//   sufDenP[p] = sum_{q>=p} exp(s2s[q])        (descending prefix)
// one block (1024 threads = 16 waves) per batch.
// ---------------------------------------------------------------------------
__global__ __launch_bounds__(1024) void k2_sort(const float* __restrict__ s2,
                                                float* __restrict__ s2s,
                                                int* __restrict__ idxs,
                                                float* __restrict__ preDenA,
                                                float* __restrict__ sufDenP) {
  __shared__ float v[2048];
  __shared__ int id[2048];
  __shared__ float wtotA[16];
  __shared__ float wtotP[16];
  const int tid = threadIdx.x;
  const int b = blockIdx.x;
  const int i0 = tid, i1 = tid + 1024;
  v[i0] = s2[b * GAT_N + i0];
  v[i1] = s2[b * GAT_N + i1];
  id[i0] = i0;
  id[i1] = i1;
  for (int k = 2; k <= 2048; k <<= 1) {
    for (int j = k >> 1; j > 0; j >>= 1) {
      __syncthreads();
      const int i = ((tid & ~(j - 1)) << 1) | (tid & (j - 1));
      const int ixj = i | j;
      const bool up = (i & k) == 0;
      const float va = v[i], vb = v[ixj];
      if (up ? (va > vb) : (va < vb)) {
        v[i] = vb;
        v[ixj] = va;
        const int ta = id[i];
        id[i] = id[ixj];
        id[ixj] = ta;
      }
    }
  }
  __syncthreads();
  s2s[b * GAT_N + i0] = v[i0];
  s2s[b * GAT_N + i1] = v[i1];
  idxs[b * GAT_N + i0] = id[i0];
  idxs[b * GAT_N + i1] = id[i1];

  // hierarchical scan: thread owns ascending pair (2t,2t+1) for preDenA and
  // descending pair (2047-2t, 2046-2t) for sufDenP.
  const int lane = tid & 63, w = tid >> 6;
  const float aL = __expf(GAT_ALPHA * v[2 * tid]);
  const float aR = __expf(GAT_ALPHA * v[2 * tid + 1]);
  const float pL = __expf(v[2047 - 2 * tid]);
  const float pR = __expf(v[2046 - 2 * tid]);
  float sA = aL + aR, sP = pL + pR;
#pragma unroll
  for (int off = 1; off < 64; off <<= 1) {
    const float tA = __shfl_up(sA, off);
    const float tP = __shfl_up(sP, off);
    if (lane >= off) {
      sA += tA;
      sP += tP;
    }
  }
  if (lane == 63) {
    wtotA[w] = sA;
    wtotP[w] = sP;
  }
  __syncthreads();
  float offA = 0.f, offP = 0.f;
  for (int ww = 0; ww < w; ++ww) {
    offA += wtotA[ww];
    offP += wtotP[ww];
  }
  const float inclA = offA + sA;
  const float inclP = offP + sP;
  preDenA[b * GAT_N + 2 * tid] = inclA - aR;
  preDenA[b * GAT_N + 2 * tid + 1] = inclA;
  sufDenP[b * GAT_N + 2047 - 2 * tid] = inclP - pR;
  sufDenP[b * GAT_N + 2046 - 2 * tid] = inclP;
}

// ---------------------------------------------------------------------------
// K3: per-(batch,chunk) partial sums of w*h over the chunk (both weightings).
// ---------------------------------------------------------------------------
__global__ __launch_bounds__(128) void k3_partial(const float* __restrict__ h,
                                                  const float* __restrict__ s2s,
                                                  const int* __restrict__ idxs,
                                                  float* __restrict__ partP,
                                                  float* __restrict__ partA) {
  const int b = blockIdx.x >> 6, c = blockIdx.x & (CH - 1);
  const int d = threadIdx.x;
  const int q0 = c * CL;
  const float* s2sb = s2s + b * GAT_N;
  const int* idxb = idxs + b * GAT_N;
  const float* hb = h + (size_t)b * GAT_N * GAT_D;
  float accP = 0.f, accA = 0.f;
#pragma unroll 4
  for (int q = q0; q < q0 + CL; ++q) {
    const float sv = s2sb[q];
    const int j = idxb[q];
    const float hv = hb[(size_t)j * GAT_D + d];
    accP = fmaf(__expf(sv), hv, accP);
    accA = fmaf(__expf(GAT_ALPHA * sv), hv, accA);
  }
  partP[(b * CH + c) * GAT_D + d] = accP;
  partA[(b * CH + c) * GAT_D + d] = accA;
}

// ---------------------------------------------------------------------------
// K4: emit full vector cumsums.
//   PreA[p][d] = sum_{q<=p} exp(alpha*s2s[q]) * h[idx[q]][d]   (prefix)
//   SufP[p][d] = sum_{q>=p} exp(s2s[q])       * h[idx[q]][d]   (suffix)
// ---------------------------------------------------------------------------
__global__ __launch_bounds__(128) void k4_emit(const float* __restrict__ h,
                                               const float* __restrict__ s2s,
                                               const int* __restrict__ idxs,
                                               const float* __restrict__ partP,
                                               const float* __restrict__ partA,
                                               float* __restrict__ PreA,
                                               float* __restrict__ SufP) {
  const int b = blockIdx.x >> 6, c = blockIdx.x & (CH - 1);
  const int d = threadIdx.x;
  const int q0 = c * CL;
  float offA = 0.f, offP = 0.f;
  for (int cc = 0; cc < c; ++cc) offA += partA[(b * CH + cc) * GAT_D + d];
  for (int cc = c + 1; cc < CH; ++cc) offP += partP[(b * CH + cc) * GAT_D + d];
  const float* s2sb = s2s + b * GAT_N;
  const int* idxb = idxs + b * GAT_N;
  const float* hb = h + (size_t)b * GAT_N * GAT_D;
  float acc = offA;
#pragma unroll 4
  for (int q = q0; q < q0 + CL; ++q) {
    acc = fmaf(__expf(GAT_ALPHA * s2sb[q]), hb[(size_t)idxb[q] * GAT_D + d], acc);
    PreA[((size_t)b * GAT_N + q) * GAT_D + d] = acc;
  }
  acc = offP;
#pragma unroll 4
  for (int q = q0 + CL - 1; q >= q0; --q) {
    acc = fmaf(__expf(s2sb[q]), hb[(size_t)idxb[q] * GAT_D + d], acc);
    SufP[((size_t)b * GAT_N + q) * GAT_D + d] = acc;
  }
}

// ---------------------------------------------------------------------------
// K5: per row -- binary search split point, combine suffix/prefix sums,
// normalize, relu. one wave per row.
// ---------------------------------------------------------------------------
__global__ __launch_bounds__(256) void k5_out(const float* __restrict__ s1,
                                              const float* __restrict__ s2s,
                                              const float* __restrict__ preDenA,
                                              const float* __restrict__ sufDenP,
                                              const float* __restrict__ PreA,
                                              const float* __restrict__ SufP,
                                              float* __restrict__ out) {
  const int wave = threadIdx.x >> 6, lane = threadIdx.x & 63;
  const int r = blockIdx.x * 4 + wave;
  const int b = r >> 11;
  const float s1v = s1[r];
  const float* s2sb = s2s + b * GAT_N;
  const float t = -s1v;
  int lo = 0, hi = GAT_N;
  while (lo < hi) {
    const int mid = (lo + hi) >> 1;
    if (s2sb[mid] < t)
      lo = mid + 1;
    else
      hi = mid;
  }
  const int p = lo;  // first sorted pos with s2 >= -s1 (plain branch)
  const float e1 = __expf(s1v), e2 = __expf(GAT_ALPHA * s1v);
  float den = 0.f, n0 = 0.f, n1 = 0.f;
  if (p < GAT_N) {
    den = fmaf(e1, sufDenP[b * GAT_N + p], den);
    const float* sp = SufP + ((size_t)b * GAT_N + p) * GAT_D;
    n0 = fmaf(e1, sp[lane], n0);
    n1 = fmaf(e1, sp[lane + 64], n1);
  }
  if (p > 0) {
    den = fmaf(e2, preDenA[b * GAT_N + p - 1], den);
    const float* pa = PreA + ((size_t)b * GAT_N + p - 1) * GAT_D;
    n0 = fmaf(e2, pa[lane], n0);
    n1 = fmaf(e2, pa[lane + 64], n1);
  }
  const float inv = 1.f / den;
  out[(size_t)r * GAT_D + lane] = fmaxf(n0 * inv, 0.f);
  out[(size_t)r * GAT_D + lane + 64] = fmaxf(n1 * inv, 0.f);
}

extern "C" void kernel_launch(void* const* d_in, const int* in_sizes, int n_in,
                              void* d_out, int out_size, void* d_ws, size_t ws_size,
                              hipStream_t stream) {
  (void)in_sizes;
  (void)n_in;
  (void)out_size;
  const float* x = (const float*)d_in[0];
  const float* W = (const float*)d_in[1];
  const float* a = (const float*)d_in[2];
  float* out = (float*)d_out;
  float* wsf = (float*)d_ws;

  const size_t HN = (size_t)GAT_ROWS * GAT_D;
  size_t o = 0;
  float* s1v = wsf + o;     o += GAT_ROWS;
  float* s2v = wsf + o;     o += GAT_ROWS;
  float* s2s = wsf + o;     o += GAT_ROWS;
  int* idxs = (int*)(wsf + o); o += GAT_ROWS;
  float* preDenA = wsf + o; o += GAT_ROWS;
  float* sufDenP = wsf + o; o += GAT_ROWS;
  float* PreA = wsf + o;    o += HN;
  float* SufP = wsf + o;    o += HN;
  float* partP = wsf + o;   o += GAT_B * CH * GAT_D;
  float* partA = wsf + o;   o += GAT_B * CH * GAT_D;
  float* h;
  if (ws_size >= (o + HN) * sizeof(float)) {
    h = wsf + o;
  } else {
    h = out;  // K5 never reads h; safe to reuse the output buffer as scratch
  }

  k1_gemm<<<1024, 256, 0, stream>>>(x, W, a, h, s1v, s2v);
  k2_sort<<<GAT_B, 1024, 0, stream>>>(s2v, s2s, idxs, preDenA, sufDenP);
  k3_partial<<<GAT_B * CH, 128, 0, stream>>>(h, s2s, idxs, partP, partA);
  k4_emit<<<GAT_B * CH, 128, 0, stream>>>(h, s2s, idxs, partP, partA, PreA, SufP);
  k5_out<<<GAT_ROWS / 4, 256, 0, stream>>>(s1v, s2s, preDenA, sufDenP, PreA, SufP, out);
}